// Round 1
// baseline (189.310 us; speedup 1.0000x reference)
//
#include <hip/hip_runtime.h>
#include <hip/hip_bf16.h>
#include <math.h>

#define BN 2048   // batch / num nodes
#define KF 512    // IN_F
#define OF 512    // OUT_F
#define NH 8      // heads
#define DD 64     // head dim

// Kernel 1: h = x @ W^T + b, plus per-head s_src/s_dst = h . a
// grid (NH, BN/64), 256 threads. N-tile of 64 == one head.
__global__ __launch_bounds__(256) void k_gemm(
    const float* __restrict__ x, const float* __restrict__ W,
    const float* __restrict__ Wb, const float* __restrict__ a,
    float* __restrict__ h, float* __restrict__ sS, float* __restrict__ sD) {
  __shared__ float xsT[32][68];   // [k][i] transposed, stride 68 (16B-aligned rows)
  __shared__ float wsT[32][68];   // [k][f]
  __shared__ float red[64][17];

  const int t  = threadIdx.x;
  const int hh = blockIdx.x;
  const int i0 = blockIdx.y * 64;
  const int f0 = hh * 64;
  const int tx = t & 15, ty = t >> 4;

  float acc[4][4] = {{0.f}};

  for (int k0 = 0; k0 < KF; k0 += 32) {
#pragma unroll
    for (int rep = 0; rep < 2; ++rep) {
      const int flat = (t + rep * 256) * 4;   // 0..2047
      const int r = flat >> 5;                // row 0..63
      const int c = flat & 31;                // k 0,4,...,28
      const float4 xv = *reinterpret_cast<const float4*>(&x[(size_t)(i0 + r) * KF + k0 + c]);
      xsT[c + 0][r] = xv.x; xsT[c + 1][r] = xv.y; xsT[c + 2][r] = xv.z; xsT[c + 3][r] = xv.w;
      const float4 wv = *reinterpret_cast<const float4*>(&W[(size_t)(f0 + r) * KF + k0 + c]);
      wsT[c + 0][r] = wv.x; wsT[c + 1][r] = wv.y; wsT[c + 2][r] = wv.z; wsT[c + 3][r] = wv.w;
    }
    __syncthreads();
#pragma unroll
    for (int kk = 0; kk < 32; ++kk) {
      const float4 av = *reinterpret_cast<const float4*>(&xsT[kk][ty * 4]);
      const float4 bv = *reinterpret_cast<const float4*>(&wsT[kk][tx * 4]);
      const float* ap = (const float*)&av;
      const float* bp = (const float*)&bv;
#pragma unroll
      for (int r = 0; r < 4; ++r)
#pragma unroll
        for (int c = 0; c < 4; ++c)
          acc[r][c] = fmaf(ap[r], bp[c], acc[r][c]);
    }
    __syncthreads();
  }

  // epilogue: bias, store h, partial s_src/s_dst
  float asrc[4], adst[4], bias[4];
#pragma unroll
  for (int c = 0; c < 4; ++c) {
    asrc[c] = a[tx * 4 + c];
    adst[c] = a[DD + tx * 4 + c];
    bias[c] = Wb[f0 + tx * 4 + c];
  }
  float psrc[4], pdst[4];
#pragma unroll
  for (int r = 0; r < 4; ++r) {
    float4 hv;
    float* hp = (float*)&hv;
    float ps = 0.f, pd = 0.f;
#pragma unroll
    for (int c = 0; c < 4; ++c) {
      const float v = acc[r][c] + bias[c];
      hp[c] = v;
      ps = fmaf(v, asrc[c], ps);
      pd = fmaf(v, adst[c], pd);
    }
    *reinterpret_cast<float4*>(&h[(size_t)(i0 + ty * 4 + r) * OF + f0 + tx * 4]) = hv;
    psrc[r] = ps; pdst[r] = pd;
  }
#pragma unroll
  for (int r = 0; r < 4; ++r) red[ty * 4 + r][tx] = psrc[r];
  __syncthreads();
  if (t < 64) {
    float s = 0.f;
#pragma unroll
    for (int q = 0; q < 16; ++q) s += red[t][q];
    sS[hh * BN + i0 + t] = s;
  }
  __syncthreads();
#pragma unroll
  for (int r = 0; r < 4; ++r) red[ty * 4 + r][tx] = pdst[r];
  __syncthreads();
  if (t < 64) {
    float s = 0.f;
#pragma unroll
    for (int q = 0; q < 16; ++q) s += red[t][q];
    sD[hh * BN + i0 + t] = s;
  }
}

// Kernel 2: fused mask/softmax-weight/PV/normalize/ELU.
// grid (NH, BN/32), 256 threads. Block = 32 i-rows x 1 head, loops all j in 64-chunks.
__global__ __launch_bounds__(256) void k_attn(
    const float* __restrict__ h, const int* __restrict__ adj,
    const float* __restrict__ sS, const float* __restrict__ sD,
    float* __restrict__ out) {
  __shared__ float hs[64][64];    // [j][d] 16KB
  __shared__ float wsm[32][68];   // [i][j] padded stride 68
  __shared__ float ssl[32];
  __shared__ float sdl[64];

  const int t  = threadIdx.x;
  const int hh = blockIdx.x;
  const int i0 = blockIdx.y * 32;
  const int d4 = (t & 15) * 4;
  const int r0 = (t >> 4) * 2;

  if (t < 32) ssl[t] = sS[hh * BN + i0 + t];

  float4 acc0 = {0, 0, 0, 0}, acc1 = {0, 0, 0, 0};
  float den0 = 0.f, den1 = 0.f;

  for (int j0 = 0; j0 < BN; j0 += 64) {
    __syncthreads();  // previous-iter readers of hs/wsm/sdl done
    if (t < 64) sdl[t] = sD[hh * BN + j0 + t];
#pragma unroll
    for (int rep = 0; rep < 4; ++rep) {
      const int q = rep * 1024 + t * 4;
      const int j = q >> 6, d = q & 63;
      *reinterpret_cast<float4*>(&hs[j][d]) =
          *reinterpret_cast<const float4*>(&h[(size_t)(j0 + j) * OF + hh * DD + d]);
    }
    __syncthreads();  // sdl/ssl ready for w computation
    {
      const int jj = t & 63;
      const int ib = (t >> 6) * 8;
#pragma unroll
      for (int k = 0; k < 8; ++k) {
        const int i = ib + k;
        const int ad = adj[(size_t)(i0 + i) * BN + j0 + jj];
        const float s = ssl[i] + sdl[jj];
        const float e = s > 0.f ? s : 0.2f * s;
        wsm[i][jj] = ad ? __expf(e) : 0.f;
      }
    }
    __syncthreads();  // wsm + hs ready
#pragma unroll
    for (int j = 0; j < 64; j += 4) {
      const float4 w0 = *reinterpret_cast<const float4*>(&wsm[r0][j]);
      const float4 w1 = *reinterpret_cast<const float4*>(&wsm[r0 + 1][j]);
      const float* w0p = (const float*)&w0;
      const float* w1p = (const float*)&w1;
#pragma unroll
      for (int q = 0; q < 4; ++q) {
        const float4 hv = *reinterpret_cast<const float4*>(&hs[j + q][d4]);
        acc0.x = fmaf(w0p[q], hv.x, acc0.x);
        acc0.y = fmaf(w0p[q], hv.y, acc0.y);
        acc0.z = fmaf(w0p[q], hv.z, acc0.z);
        acc0.w = fmaf(w0p[q], hv.w, acc0.w);
        acc1.x = fmaf(w1p[q], hv.x, acc1.x);
        acc1.y = fmaf(w1p[q], hv.y, acc1.y);
        acc1.z = fmaf(w1p[q], hv.z, acc1.z);
        acc1.w = fmaf(w1p[q], hv.w, acc1.w);
        den0 += w0p[q];
        den1 += w1p[q];
      }
    }
  }

  const float n0 = 1.f / den0, n1 = 1.f / den1;
  float o0[4], o1[4];
  const float* a0 = (const float*)&acc0;
  const float* a1 = (const float*)&acc1;
#pragma unroll
  for (int q = 0; q < 4; ++q) {
    const float v0 = a0[q] * n0;
    const float v1 = a1[q] * n1;
    o0[q] = v0 > 0.f ? v0 : expm1f(v0);
    o1[q] = v1 > 0.f ? v1 : expm1f(v1);
  }
  *reinterpret_cast<float4*>(&out[(size_t)(i0 + r0) * OF + hh * DD + d4]) =
      *reinterpret_cast<const float4*>(o0);
  *reinterpret_cast<float4*>(&out[(size_t)(i0 + r0 + 1) * OF + hh * DD + d4]) =
      *reinterpret_cast<const float4*>(o1);
}

extern "C" void kernel_launch(void* const* d_in, const int* in_sizes, int n_in,
                              void* d_out, int out_size, void* d_ws, size_t ws_size,
                              hipStream_t stream) {
  const float* x  = (const float*)d_in[0];
  const int* adj  = (const int*)d_in[1];
  const float* Ww = (const float*)d_in[2];
  const float* Wb = (const float*)d_in[3];
  const float* a  = (const float*)d_in[4];
  float* outp = (float*)d_out;

  float* h  = (float*)d_ws;                    // BN*OF floats = 4 MB
  float* sS = h + (size_t)BN * OF;             // NH*BN
  float* sD = sS + (size_t)NH * BN;            // NH*BN

  k_gemm<<<dim3(NH, BN / 64), 256, 0, stream>>>(x, Ww, Wb, a, h, sS, sD);
  k_attn<<<dim3(NH, BN / 32), 256, 0, stream>>>(h, adj, sS, sD, outp);
}

// Round 2
// 55.922 us; speedup vs baseline: 3.3853x; 3.3853x over previous
//
#include <hip/hip_runtime.h>
#include <math.h>
#include <stdint.h>

#define BN 2048   // nodes
#define KF 512    // IN_F
#define OF 512    // OUT_F
#define NH 8      // heads
#define DD 64     // head dim
#define IT 32     // i-tile (k_attn)
#define JT 64     // j-chunk (k_attn)

typedef __attribute__((ext_vector_type(8))) short short8;
typedef __attribute__((ext_vector_type(4))) float f32x4;

static __device__ __forceinline__ unsigned short f2bf(float f) {
  unsigned u = __float_as_uint(f);
  u += 0x7fffu + ((u >> 16) & 1u);           // round-to-nearest-even
  return (unsigned short)(u >> 16);
}
static __device__ __forceinline__ float bf2f(unsigned short b) {
  return __uint_as_float(((unsigned)b) << 16);
}

// ---------------- adj -> bitmask bytes (adjB[i][b] bit e = adj[i][b*8+e]!=0)
__global__ __launch_bounds__(256) void k_pack(const int* __restrict__ adj,
                                              uint8_t* __restrict__ adjB) {
  const int b = blockIdx.x * 256 + threadIdx.x;       // byte index
  const int4 v0 = *(const int4*)(adj + (size_t)b * 8);
  const int4 v1 = *(const int4*)(adj + (size_t)b * 8 + 4);
  unsigned m = (v0.x ? 1u : 0u) | (v0.y ? 2u : 0u) | (v0.z ? 4u : 0u) | (v0.w ? 8u : 0u)
             | (v1.x ? 16u : 0u) | (v1.y ? 32u : 0u) | (v1.z ? 64u : 0u) | (v1.w ? 128u : 0u);
  adjB[b] = (uint8_t)m;
}

// ---------------- h = x@W^T + b ; store h^T in bf16 ; E-tables exp(s), exp(0.2s)
__global__ __launch_bounds__(256) void k_gemm(
    const float* __restrict__ x, const float* __restrict__ W,
    const float* __restrict__ Wb, const float* __restrict__ a,
    unsigned short* __restrict__ hbT,
    float* __restrict__ E1s, float* __restrict__ E2s,
    float* __restrict__ E1d, float* __restrict__ E2d) {
  __shared__ float xsT[32][68];
  __shared__ float wsT[32][68];
  __shared__ float red[64][17];

  const int t  = threadIdx.x;
  const int hh = blockIdx.x;
  const int i0 = blockIdx.y * 64;
  const int f0 = hh * 64;
  const int tx = t & 15, ty = t >> 4;

  float acc[4][4] = {{0.f}};

  for (int k0 = 0; k0 < KF; k0 += 32) {
#pragma unroll
    for (int rep = 0; rep < 2; ++rep) {
      const int flat = (t + rep * 256) * 4;
      const int r = flat >> 5;
      const int c = flat & 31;
      const float4 xv = *reinterpret_cast<const float4*>(&x[(size_t)(i0 + r) * KF + k0 + c]);
      xsT[c + 0][r] = xv.x; xsT[c + 1][r] = xv.y; xsT[c + 2][r] = xv.z; xsT[c + 3][r] = xv.w;
      const float4 wv = *reinterpret_cast<const float4*>(&W[(size_t)(f0 + r) * KF + k0 + c]);
      wsT[c + 0][r] = wv.x; wsT[c + 1][r] = wv.y; wsT[c + 2][r] = wv.z; wsT[c + 3][r] = wv.w;
    }
    __syncthreads();
#pragma unroll
    for (int kk = 0; kk < 32; ++kk) {
      const float4 av = *reinterpret_cast<const float4*>(&xsT[kk][ty * 4]);
      const float4 bv = *reinterpret_cast<const float4*>(&wsT[kk][tx * 4]);
      const float* ap = (const float*)&av;
      const float* bp = (const float*)&bv;
#pragma unroll
      for (int r = 0; r < 4; ++r)
#pragma unroll
        for (int c = 0; c < 4; ++c)
          acc[r][c] = fmaf(ap[r], bp[c], acc[r][c]);
    }
    __syncthreads();
  }

  float asrc[4], adst[4], bias[4];
#pragma unroll
  for (int c = 0; c < 4; ++c) {
    asrc[c] = a[tx * 4 + c];
    adst[c] = a[DD + tx * 4 + c];
    bias[c] = Wb[f0 + tx * 4 + c];
  }
  float v[4][4], psrc[4], pdst[4];
#pragma unroll
  for (int r = 0; r < 4; ++r) {
    float ps = 0.f, pd = 0.f;
#pragma unroll
    for (int c = 0; c < 4; ++c) {
      v[r][c] = acc[r][c] + bias[c];
      ps = fmaf(v[r][c], asrc[c], ps);
      pd = fmaf(v[r][c], adst[c], pd);
    }
    psrc[r] = ps; pdst[r] = pd;
  }
  // transposed bf16 store: hbT[d][i]
#pragma unroll
  for (int c = 0; c < 4; ++c) {
    ushort4 u;
    u.x = f2bf(v[0][c]); u.y = f2bf(v[1][c]); u.z = f2bf(v[2][c]); u.w = f2bf(v[3][c]);
    *reinterpret_cast<ushort4*>(&hbT[(size_t)(f0 + tx * 4 + c) * BN + i0 + ty * 4]) = u;
  }
#pragma unroll
  for (int r = 0; r < 4; ++r) red[ty * 4 + r][tx] = psrc[r];
  __syncthreads();
  if (t < 64) {
    float s = 0.f;
#pragma unroll
    for (int q = 0; q < 16; ++q) s += red[t][q];
    E1s[hh * BN + i0 + t] = __expf(s);
    E2s[hh * BN + i0 + t] = __expf(0.2f * s);
  }
  __syncthreads();
#pragma unroll
  for (int r = 0; r < 4; ++r) red[ty * 4 + r][tx] = pdst[r];
  __syncthreads();
  if (t < 64) {
    float s = 0.f;
#pragma unroll
    for (int q = 0; q < 16; ++q) s += red[t][q];
    E1d[hh * BN + i0 + t] = __expf(s);
    E2d[hh * BN + i0 + t] = __expf(0.2f * s);
  }
}

// ---------------- fused mask/weight/PV(MFMA)/normalize/ELU
__global__ __launch_bounds__(256) void k_attn(
    const unsigned short* __restrict__ hbT, const uint8_t* __restrict__ adjB,
    const float* __restrict__ E1s, const float* __restrict__ E2s,
    const float* __restrict__ E1d, const float* __restrict__ E2d,
    float* __restrict__ out) {
  __shared__ unsigned short hB[64 * 64];   // [n][k] swizzled, 8 KB
  __shared__ unsigned short wA[32 * 64];   // [i][k] swizzled, 4 KB
  __shared__ float e1d[BN];                // 8 KB
  __shared__ float e2d[BN];                // 8 KB
  __shared__ uint8_t abits[32 * 272];      // 8.5 KB, padded row stride
  __shared__ float denl[32];

  const int t    = threadIdx.x;
  const int hh   = blockIdx.x;
  const int i0   = blockIdx.y * IT;
  const int lane = t & 63;
  const int wv   = t >> 6;

  // one-time staging: E1d/E2d rows + adj bit rows
  {
    const float4* g1 = (const float4*)(E1d + (size_t)hh * BN);
    const float4* g2 = (const float4*)(E2d + (size_t)hh * BN);
    ((float4*)e1d)[t] = g1[t]; ((float4*)e1d)[t + 256] = g1[t + 256];
    ((float4*)e2d)[t] = g2[t]; ((float4*)e2d)[t + 256] = g2[t + 256];
    const int r = t >> 3, p = t & 7;
    const int4* g = (const int4*)(adjB + (size_t)(i0 + r) * 256 + p * 32);
    int4 b0 = g[0], b1 = g[1];
    *(int4*)(abits + r * 272 + p * 32)      = b0;
    *(int4*)(abits + r * 272 + p * 32 + 16) = b1;
  }

  // w-compute mapping: 8 threads per i-row, 8 j's each
  const int wi = t >> 3;
  const int jg = t & 7;
  const float e1i = E1s[(size_t)hh * BN + i0 + wi];
  const float e2i = E2s[(size_t)hh * BN + i0 + wi];
  float denp = 0.f;

  // mfma assignment: wave -> (Mtile, 2 Ntiles)
  const int mt   = wv & 1;
  const int nt0  = (wv >> 1) * 2;
  const int l15  = lane & 15;
  const int kq   = lane >> 4;
  const int arow = mt * 16 + l15;
  const int bn0  = nt0 * 16 + l15;
  f32x4 acc0 = {0.f, 0.f, 0.f, 0.f}, acc1 = {0.f, 0.f, 0.f, 0.f};

  // software-pipelined hB staging registers (2 slots/thread)
  int4 hv0, hv1;
  {
    const int S0 = t, S1 = t + 256;
    hv0 = *(const int4*)(hbT + (size_t)(hh * 64 + (S0 >> 3)) * BN + 0 + (S0 & 7) * 8);
    hv1 = *(const int4*)(hbT + (size_t)(hh * 64 + (S1 >> 3)) * BN + 0 + (S1 & 7) * 8);
  }

  for (int j0 = 0; j0 < BN; j0 += JT) {
    __syncthreads();  // previous mfma done reading hB/wA (and first-iter staging done)

    // write staged h regs -> swizzled LDS
    {
      const int n0 = t >> 3, s0 = t & 7;
      *(int4*)(hB + n0 * 64 + ((s0 ^ (n0 & 7)) * 8)) = hv0;
      const int S1 = t + 256;
      const int n1 = S1 >> 3, s1 = S1 & 7;
      *(int4*)(hB + n1 * 64 + ((s1 ^ (n1 & 7)) * 8)) = hv1;
    }

    // compute w for 8 j's
    {
      const uint64_t bits64 = *(const uint64_t*)(abits + wi * 272 + (j0 >> 3));
      const unsigned bbyte = (unsigned)(bits64 >> (jg * 8)) & 0xffu;
      float d1[8], d2[8];
      *(float4*)&d1[0] = *(const float4*)(e1d + j0 + jg * 8);
      *(float4*)&d1[4] = *(const float4*)(e1d + j0 + jg * 8 + 4);
      *(float4*)&d2[0] = *(const float4*)(e2d + j0 + jg * 8);
      *(float4*)&d2[4] = *(const float4*)(e2d + j0 + jg * 8 + 4);
      short8 wb;
#pragma unroll
      for (int e = 0; e < 8; ++e) {
        const float p1 = e1i * d1[e];
        const float p2 = e2i * d2[e];
        float w = p1 > 1.f ? p1 : p2;
        w = ((bbyte >> e) & 1u) ? w : 0.f;
        const unsigned short wu = f2bf(w);
        wb[e] = (short)wu;
        denp += bf2f(wu);     // den from the bf16-rounded values (error cancels)
      }
      *(short8*)(wA + wi * 64 + ((jg ^ (wi & 7)) * 8)) = wb;
    }

    // prefetch next chunk's h regs (overlaps with mfma below)
    if (j0 + JT < BN) {
      const int S0 = t, S1 = t + 256;
      hv0 = *(const int4*)(hbT + (size_t)(hh * 64 + (S0 >> 3)) * BN + (j0 + JT) + (S0 & 7) * 8);
      hv1 = *(const int4*)(hbT + (size_t)(hh * 64 + (S1 >> 3)) * BN + (j0 + JT) + (S1 & 7) * 8);
    }

    __syncthreads();  // hB + wA ready

#pragma unroll
    for (int kb = 0; kb < 2; ++kb) {
      const int ks = kb * 4 + kq;   // 16B chunk index 0..7
      const short8 af  = *(const short8*)(wA + arow * 64 + ((ks ^ (arow & 7)) * 8));
      const short8 bf0 = *(const short8*)(hB + bn0 * 64 + ((ks ^ (bn0 & 7)) * 8));
      const short8 bf1 = *(const short8*)(hB + (bn0 + 16) * 64 + ((ks ^ (bn0 & 7)) * 8));
      acc0 = __builtin_amdgcn_mfma_f32_16x16x32_bf16(af, bf0, acc0, 0, 0, 0);
      acc1 = __builtin_amdgcn_mfma_f32_16x16x32_bf16(af, bf1, acc1, 0, 0, 0);
    }
  }

  // finalize den: reduce over the 8 threads sharing an i-row
  {
    float d = denp;
    d += __shfl_xor(d, 1);
    d += __shfl_xor(d, 2);
    d += __shfl_xor(d, 4);
    if ((t & 7) == 0) denl[wi] = d;
  }
  __syncthreads();

  // epilogue: normalize + ELU + store
#pragma unroll
  for (int q = 0; q < 4; ++q) {
    const int row = mt * 16 + kq * 4 + q;
    const float rd = 1.f / denl[row];
    float v0 = acc0[q] * rd;
    float v1 = acc1[q] * rd;
    v0 = v0 > 0.f ? v0 : expm1f(v0);
    v1 = v1 > 0.f ? v1 : expm1f(v1);
    out[(size_t)(i0 + row) * OF + hh * 64 + nt0 * 16 + l15]      = v0;
    out[(size_t)(i0 + row) * OF + hh * 64 + (nt0 + 1) * 16 + l15] = v1;
  }
}

extern "C" void kernel_launch(void* const* d_in, const int* in_sizes, int n_in,
                              void* d_out, int out_size, void* d_ws, size_t ws_size,
                              hipStream_t stream) {
  const float* x  = (const float*)d_in[0];
  const int* adj  = (const int*)d_in[1];
  const float* Ww = (const float*)d_in[2];
  const float* Wb = (const float*)d_in[3];
  const float* a  = (const float*)d_in[4];
  float* outp = (float*)d_out;

  uint8_t* wsb = (uint8_t*)d_ws;
  unsigned short* hbT = (unsigned short*)wsb;                 // 512*2048 bf16 = 2 MB
  float* E1s = (float*)(wsb + 2097152);                       // 8*2048 f32 each
  float* E2s = E1s + (size_t)NH * BN;
  float* E1d = E2s + (size_t)NH * BN;
  float* E2d = E1d + (size_t)NH * BN;
  uint8_t* adjB = wsb + 2097152 + 4 * (size_t)NH * BN * 4;    // 2048*256 bytes

  k_pack<<<dim3(BN * 256 / 256), 256, 0, stream>>>(adj, adjB);
  k_gemm<<<dim3(NH, BN / 64), 256, 0, stream>>>(x, Ww, Wb, a, hbT, E1s, E2s, E1d, E2d);
  k_attn<<<dim3(NH, BN / IT), 256, 0, stream>>>(hbT, adjB, E1s, E2s, E1d, E2d, outp);
}